// Round 7
// baseline (186.226 us; speedup 1.0000x reference)
//
#include <hip/hip_runtime.h>
#include <hip/hip_bf16.h>

// SO3TensorProductLayer: out = relu(128*(x (x) x) @ W1 + b1) @ W2 + b2
// v10: SYMMETRY FOLD. h[b,c] = sum_{i<=j} W1s[ij,c] x_i x_j with
// W1s[ij] = W1[ij]+W1[ji] (j>i), W1[ii] (j=i), 0 (j<i within partial
// chunk). Per i-chunk z only j-chunks kc>=z survive -> 10/16 of the
// MFMA work (62.5%), exact identity. One block owns full K -> Pb
// partials ELIMINATED (was 16.8MB write + read); gemm writes h (4.2MB
// bf16) with relu+bias fused; tail = tiny gemm2 only.
// Schedule side is the r0/v7-proven idiom (acc-side xi fold, Ar ring,
// static indices under unroll-2); MfmaUtil plateau ~32% accepted --
// seven variants (occupancy/L2/ring/DAG/tile) all failed to move it,
// so we cut work instead. Grid 512 (2 blocks/CU), block c64 x b64,
// wave c32 x b32; XCD swizzle: c-block == XCD -> A-slice 1.31MB
// L2-resident (v7-proven, FETCH 72->24MB held).
// REGALLOC (r5/rule20): all vector arrays statically indexed (unrolled).

typedef __attribute__((ext_vector_type(8))) short short8;   // 8 bf16
typedef __attribute__((ext_vector_type(4))) float floatx4;  // 4 fp32

__device__ __forceinline__ unsigned short f2bf(float f) {
    union { float f; unsigned int u; } v; v.f = f;
    unsigned int r = v.u + 0x7fffu + ((v.u >> 16) & 1u);   // RNE
    return (unsigned short)(r >> 16);
}

// ---------------------------------------------------------------------------
// prep: blocks 0..319 pack symmetric-folded W1 -> W1p; 320..351 transpose
// W2 -> W2T bf16.
// W1p stream per c16 (320 chunks of 1KB): for i (i-major), kc in [i>>5,4):
// chunk idx = cum[z] + il*(4-z) + (kc-z), cum = {0,128,224,288}, z=i>>5.
// Chunk (c16,i,kc): lane(m=lane&15,quad) elem e holds bf16 of
// W1s[K=kc*32+quad*8+e (=j), i][c=c16*16+m].
__global__ __launch_bounds__(256) void prep_kernel(
    const float* __restrict__ W1, unsigned short* __restrict__ W1p,
    const float* __restrict__ W2, unsigned short* __restrict__ W2T) {
    __shared__ float tile[64][65];
    const int bx = blockIdx.x;
    if (bx < 320) {
        const int cb = bx & 7;                 // c-block (64 c)
        const int ih = (bx >> 3) & 3;          // i-eighth (8 i's)
        const int p  = bx >> 5;                // pair 0..9
        int zi, zj;
        if (p < 4)      { zi = 0; zj = p; }
        else if (p < 7) { zi = 1; zj = p - 3; }
        else if (p < 9) { zi = 2; zj = p - 5; }
        else            { zi = 3; zj = 3; }
        const int lane = threadIdx.x & 63;
        const int w = threadIdx.x >> 6;        // wave -> c16 within cb
        const int m = lane & 15, quad = lane >> 4;
        const int c16 = cb * 4 + w;
        const int c = c16 * 16 + m;
        const int cum = (zi == 0) ? 0 : (zi == 1) ? 128 : (zi == 2) ? 224 : 288;
        for (int il8 = 0; il8 < 8; ++il8) {
            const int il = ih * 8 + il8;
            const int i_g = zi * 32 + il;
            union { unsigned short s[8]; uint4 u; } o;
#pragma unroll
            for (int e = 0; e < 8; ++e) {
                const int j_g = zj * 32 + quad * 8 + e;
                float v = 0.f;
                if (j_g == i_g)
                    v = W1[((long)i_g * 128 + j_g) * 512 + c];
                else if (j_g > i_g)
                    v = W1[((long)i_g * 128 + j_g) * 512 + c]
                      + W1[((long)j_g * 128 + i_g) * 512 + c];
                o.s[e] = f2bf(v);
            }
            const long chunk = (long)c16 * 320 + cum
                             + (long)il * (4 - zi) + (zj - zi);
            *(uint4*)(W1p + chunk * 512 + lane * 8) = o.u;
        }
    } else {
        const int t = bx - 320;                // 0..31
        const int r0 = (t & 7) * 64, c0 = (t >> 3) * 64;
        const int R = 512, C = 256;
        const int tr = threadIdx.x >> 4;
        const int tc4 = (threadIdx.x & 15) * 4;
#pragma unroll
        for (int pp = 0; pp < 4; ++pp) {
            int r = pp * 16 + tr;
            float4 v = *(const float4*)(W2 + (long)(r0 + r) * C + c0 + tc4);
            tile[r][tc4 + 0] = v.x; tile[r][tc4 + 1] = v.y;
            tile[r][tc4 + 2] = v.z; tile[r][tc4 + 3] = v.w;
        }
        __syncthreads();
#pragma unroll
        for (int pp = 0; pp < 4; ++pp) {
            int cc = pp * 16 + tr;
            union { unsigned short s[4]; uint2 u; } pk;
#pragma unroll
            for (int e = 0; e < 4; ++e) pk.s[e] = f2bf(tile[tc4 + e][cc]);
            *(uint2*)(W2T + (long)(c0 + cc) * R + r0 + tc4) = pk.u;
        }
    }
}

// ---------------------------------------------------------------------------
// gemm_sym: H[b][c] = relu(128 * sum_i x_i * (sum_{kc>=z} W1s-chunk @ x) + b1)
// 256 thr = 4 waves (2wm c x 2wn b); wave c32 x b32 (tm=2, tn=2);
// block c64 x b64. Flat grid 512; XCD swizzle L=(n&7)*64+(n>>3):
// b0=(L&63)*64, c0=(L>>6)*64 -> each XCD owns one 64-c A-slice (1.31MB).

#define Z_PHASE(CH, ZB)                                                     \
    {                                                                       \
        short8 Ar[2][2][CH];                                                \
        _Pragma("unroll")                                                   \
        for (int q = 0; q < CH; ++q) {                                      \
            Ar[0][0][q] = *(const short8*)(aP0 + (long)q * 512);            \
            Ar[0][1][q] = *(const short8*)(aP1 + (long)q * 512);            \
            Ar[1][0][q] = *(const short8*)(aP0 + (long)(CH + q) * 512);     \
            Ar[1][1][q] = *(const short8*)(aP1 + (long)(CH + q) * 512);     \
        }                                                                   \
        _Pragma("unroll 2")                                                 \
        for (int il = 0; il < 32; ++il) {                                   \
            const int st = il & 1;                                          \
            float xi0 = xT[xrow0][(ZB) * 32 + il];                          \
            float xi1 = xT[xrow1][(ZB) * 32 + il];                          \
            floatx4 t00 = zero4, t01 = zero4, t10 = zero4, t11 = zero4;     \
            _Pragma("unroll")                                               \
            for (int q = 0; q < CH; ++q) {                                  \
                t00 = __builtin_amdgcn_mfma_f32_16x16x32_bf16(              \
                    Ar[st][0][q], Xf[4 - (CH) + q][0], t00, 0, 0, 0);       \
                t01 = __builtin_amdgcn_mfma_f32_16x16x32_bf16(              \
                    Ar[st][0][q], Xf[4 - (CH) + q][1], t01, 0, 0, 0);       \
                t10 = __builtin_amdgcn_mfma_f32_16x16x32_bf16(              \
                    Ar[st][1][q], Xf[4 - (CH) + q][0], t10, 0, 0, 0);       \
                t11 = __builtin_amdgcn_mfma_f32_16x16x32_bf16(              \
                    Ar[st][1][q], Xf[4 - (CH) + q][1], t11, 0, 0, 0);       \
            }                                                               \
            acc[0][0] += xi0 * t00; acc[0][1] += xi1 * t01;                 \
            acc[1][0] += xi0 * t10; acc[1][1] += xi1 * t11;                 \
            _Pragma("unroll")                                               \
            for (int q = 0; q < CH; ++q) {                                  \
                Ar[st][0][q] = *(const short8*)(aP0                         \
                    + (long)((il + 2) * (CH) + q) * 512);                   \
                Ar[st][1][q] = *(const short8*)(aP1                         \
                    + (long)((il + 2) * (CH) + q) * 512);                   \
            }                                                               \
        }                                                                   \
        aP0 += 32 * (CH) * 512;                                             \
        aP1 += 32 * (CH) * 512;                                             \
    }

__global__ __launch_bounds__(256, 2) void gemm_sym_kernel(
    const float* __restrict__ x,               // [4096][128]
    const unsigned short* __restrict__ W1p,    // packed symmetric W1
    const float* __restrict__ b1,              // [512]
    unsigned short* __restrict__ H) {          // [4096][512] bf16
    __shared__ float xT[64][129];              // [b_local][i]; odd-ish stride
    const int tid = threadIdx.x;
    const int n = blockIdx.x;
    const int L = (n & 7) * 64 + (n >> 3);     // bijective, 512 blocks
    const int b0 = (L & 63) * 64;
    const int c0 = (L >> 6) * 64;              // c-block == XCD

    // stage xT: 2048 float4s, coalesced
    for (int idx = tid; idx < 64 * 32; idx += 256) {
        int bL = idx >> 5, i4 = (idx & 31) * 4;
        float4 v = *(const float4*)(x + (long)(b0 + bL) * 128 + i4);
        xT[bL][i4 + 0] = v.x; xT[bL][i4 + 1] = v.y;
        xT[bL][i4 + 2] = v.z; xT[bL][i4 + 3] = v.w;
    }
    __syncthreads();

    const int wid = tid >> 6;
    const int wm = wid >> 1, wn = wid & 1;
    const int lane = tid & 63;
    const int n16 = lane & 15, quad = lane >> 4;
    const int bBase = b0 + wn * 32;
    const int c16base = (c0 >> 4) + wm * 2;
    const int xrow0 = wn * 32 + n16;
    const int xrow1 = xrow0 + 16;

    floatx4 acc[2][2];
#pragma unroll
    for (int tm = 0; tm < 2; ++tm)
#pragma unroll
        for (int tn = 0; tn < 2; ++tn) acc[tm][tn] = (floatx4){0.f, 0.f, 0.f, 0.f};
    const floatx4 zero4 = (floatx4){0.f, 0.f, 0.f, 0.f};

    // x j-fragments for all 4 chunks (32 VGPR), register-resident
    short8 Xf[4][2];
#pragma unroll
    for (int kc = 0; kc < 4; ++kc)
#pragma unroll
        for (int tn = 0; tn < 2; ++tn) {
            const float* xp = x + (long)(bBase + tn * 16 + n16) * 128
                                + kc * 32 + quad * 8;
            float4 v0 = *(const float4*)xp;
            float4 v1 = *(const float4*)(xp + 4);
            short8 f;
            f[0] = (short)f2bf(v0.x); f[1] = (short)f2bf(v0.y);
            f[2] = (short)f2bf(v0.z); f[3] = (short)f2bf(v0.w);
            f[4] = (short)f2bf(v1.x); f[5] = (short)f2bf(v1.y);
            f[6] = (short)f2bf(v1.z); f[7] = (short)f2bf(v1.w);
            Xf[kc][tn] = f;
        }

    const unsigned short* aP0 = W1p + (long)(c16base + 0) * 320 * 512 + lane * 8;
    const unsigned short* aP1 = W1p + (long)(c16base + 1) * 320 * 512 + lane * 8;

    Z_PHASE(4, 0)
    Z_PHASE(3, 1)
    Z_PHASE(2, 2)
    Z_PHASE(1, 3)

    // epilogue: h = relu(128*acc + b1) -> H[b][c] bf16 (4 c-consec per lane)
#pragma unroll
    for (int tm = 0; tm < 2; ++tm) {
        const int cb4 = (c16base + tm) * 16 + quad * 4;
        float4 b1v = *(const float4*)(b1 + cb4);
#pragma unroll
        for (int tn = 0; tn < 2; ++tn) {
            int b = bBase + tn * 16 + n16;
            union { unsigned short s[4]; uint2 u; } pk;
            pk.s[0] = f2bf(fmaxf(fmaf(128.f, acc[tm][tn][0], b1v.x), 0.f));
            pk.s[1] = f2bf(fmaxf(fmaf(128.f, acc[tm][tn][1], b1v.y), 0.f));
            pk.s[2] = f2bf(fmaxf(fmaf(128.f, acc[tm][tn][2], b1v.z), 0.f));
            pk.s[3] = f2bf(fmaxf(fmaf(128.f, acc[tm][tn][3], b1v.w), 0.f));
            *(uint2*)(H + (long)b * 512 + cb4) = pk.u;
        }
    }
}

// ---------------------------------------------------------------------------
// tail: out[b][o] = H @ W2T + b2. 256 thr = 4 waves; b-tile 16; each wave
// owns 64 o columns. H read direct from global (4.2MB, L3-resident).
// Block swizzle matches gemm's H-writer XCD: (t>>2)&7 == n&7.
__global__ __launch_bounds__(256) void tail_kernel(
    const unsigned short* __restrict__ H,      // [4096][512] bf16
    const unsigned short* __restrict__ W2T,    // [256][512] bf16
    const float* __restrict__ b2,              // [256]
    float* __restrict__ out) {                 // [4096][256]
    const int tid = threadIdx.x;
    const int n = blockIdx.x;
    const int v = n >> 3;
    const int bt = (n & 7) * 4 + (v & 3) + (v >> 2) * 32;  // bijective
    const int b0 = bt * 16;
    const int w = tid >> 6, lane = tid & 63;
    const int n16 = lane & 15, quad = lane >> 4;
    const int o0 = w * 64;
    floatx4 acc[4];
#pragma unroll
    for (int tn = 0; tn < 4; ++tn) acc[tn] = (floatx4){0.f, 0.f, 0.f, 0.f};

#pragma unroll 4
    for (int ks = 0; ks < 16; ++ks) {
        short8 Af = *(const short8*)(H + (long)(b0 + n16) * 512
                                     + ks * 32 + quad * 8);
        short8 Bf[4];
#pragma unroll
        for (int tn = 0; tn < 4; ++tn)
            Bf[tn] = *(const short8*)(W2T + (long)(o0 + tn * 16 + n16) * 512
                                      + ks * 32 + quad * 8);
#pragma unroll
        for (int tn = 0; tn < 4; ++tn)
            acc[tn] = __builtin_amdgcn_mfma_f32_16x16x32_bf16(
                Af, Bf[tn], acc[tn], 0, 0, 0);
    }
#pragma unroll
    for (int tn = 0; tn < 4; ++tn) {
        float bias = b2[o0 + tn * 16 + n16];
#pragma unroll
        for (int r = 0; r < 4; ++r)
            out[(long)(b0 + quad * 4 + r) * 256
                + o0 + tn * 16 + n16] = acc[tn][r] + bias;
    }
}

extern "C" void kernel_launch(void* const* d_in, const int* in_sizes, int n_in,
                              void* d_out, int out_size, void* d_ws, size_t ws_size,
                              hipStream_t stream) {
    const float* x  = (const float*)d_in[0];   // [4096,128]
    const float* W1 = (const float*)d_in[1];   // [16384,512]
    const float* b1 = (const float*)d_in[2];   // [512]
    const float* W2 = (const float*)d_in[3];   // [512,256]
    const float* b2 = (const float*)d_in[4];   // [256]
    float* out = (float*)d_out;                // [4096,256]

    char* ws = (char*)d_ws;
    unsigned short* W1p = (unsigned short*)(ws);                  // 10.49 MB
    unsigned short* W2T = (unsigned short*)(ws + 10485760);       // 0.26 MB
    unsigned short* H   = (unsigned short*)(ws + 10485760 + 262144); // 4.19 MB

    prep_kernel<<<dim3(352), 256, 0, stream>>>(W1, W1p, W2, W2T);
    gemm_sym_kernel<<<dim3(512), 256, 0, stream>>>(x, W1p, b1, H);
    tail_kernel<<<dim3(256), 256, 0, stream>>>(H, W2T, b2, out);
}

// Round 8
// 155.001 us; speedup vs baseline: 1.2015x; 1.2015x over previous
//
#include <hip/hip_runtime.h>
#include <hip/hip_bf16.h>

// SO3TensorProductLayer: out = relu(128*(x (x) x) @ W1 + b1) @ W2 + b2
// v11: symmetric fold ON the v9 schedule. v10 post-mortem: fold is exact
// (absmax 1.0) but wave c32xb32 = 4 MFMA chains -> MfmaUtil 20.7% (ILP
// curve: 4ch=20%, 8ch=28%, 16ch=32-34%); prep's scalar stride-512 W1
// reads ballooned non-gemm time. v11 restores the v9 shape exactly
// (wave c32xb128, 16 chains, ring-4, acc-side xi fold, fragment-packed
// Pb, 512 blocks = 2/CU, XCD swizzle cb==XCD) and splits the 10
// surviving (z,kc) units into 4 balanced groups of 2.5:
//   G0=(0,0)+(0,1)+half(1,3)   G1=(0,2)+(0,3)+half(1,3)
//   G2=(1,1)+(1,2)+half(3,3)   G3=(2,2)+(2,3)+half(3,3)
// Block = PHASE2 (32 il, CH=2, v9 body, advance 1024) + xT restage (16
// rows) + PHASE1H (16 il, CH=1, ring-4). Tail = v9 byte-identical.
// Prep rewritten coalesced: LDS-stage both triangle tiles (64KB),
// float4 reads both sides, sum+pack from LDS.
// W1p layout per c16 (320 chunks of 1KB): cols [g*64 + il*2 + ch] for
// the 4 CH=2 groups, [256+il] for (1,3), [288+il] for (3,3).
// REGALLOC (r5/rule20): no runtime-indexed vector arrays; named rings.

typedef __attribute__((ext_vector_type(8))) short short8;   // 8 bf16
typedef __attribute__((ext_vector_type(4))) float floatx4;  // 4 fp32

__device__ __forceinline__ unsigned short f2bf(float f) {
    union { float f; unsigned int u; } v; v.f = f;
    unsigned int r = v.u + 0x7fffu + ((v.u >> 16) & 1u);   // RNE
    return (unsigned short)(r >> 16);
}
__device__ __forceinline__ float bf2f(unsigned short b) {
    union { unsigned int u; float f; } v; v.u = ((unsigned int)b) << 16;
    return v.f;
}

// ---------------------------------------------------------------------------
// prep: blocks 0..639 pack symmetric-folded W1; 640..671 transpose W2.
// Block (u, isub, cb): u = (z,kc) unit, isub = 4-i subchunk, cb = 64-c blk.
// Stages W1 rows (i*128+j) and (j*128+i) coalesced into LDS, then packs
// W1s[j>i]=sum, [j==i]=diag, [j<i]=0 into MFMA A-fragment chunks:
// chunk(c16,i,unit): lane(m=lane&15,quad) elem e = W1s[j=kc*32+quad*8+e][i][c16*16+m].
__global__ __launch_bounds__(256) void prep_kernel(
    const float* __restrict__ W1, unsigned short* __restrict__ W1p,
    const float* __restrict__ W2, unsigned short* __restrict__ W2T) {
    __shared__ float Asm[4][32][64];           // [iL][jL][c] 32KB
    __shared__ float Bsm[32][4][64];           // [jL][iL][c] 32KB
    __shared__ float tile[64][65];
    const int bx = blockIdx.x;
    const int tid = threadIdx.x;
    if (bx < 640) {
        const int u = bx >> 6;
        const int rem = bx & 63;
        const int isub = rem >> 3, cb = rem & 7;
        const int z  = (u < 4) ? 0 : (u < 7) ? 1 : (u < 9) ? 2 : 3;
        const int kc = (u < 4) ? u : (u < 7) ? (u - 3) : (u < 9) ? (u - 5) : 3;
        int base, stride;
        if (z == 0)                 { base = (kc >> 1) * 64 + (kc & 1); stride = 2; }
        else if (z == 1 && kc < 3)  { base = 128 + (kc - 1);            stride = 2; }
        else if (z == 1)            { base = 256;                       stride = 1; }
        else if (z == 2)            { base = 192 + (kc - 2);            stride = 2; }
        else                        { base = 288;                       stride = 1; }
        const int i0g = z * 32 + isub * 4;
        const int j0g = kc * 32;
        const int c0 = cb * 64;
        // coalesced loads: 128 rows x 64 c each side (16 float4/row)
#pragma unroll
        for (int it = 0; it < 8; ++it) {
            int idx = tid + it * 256;          // 0..2047
            int r = idx >> 4;                  // 0..127
            int c4 = (idx & 15) * 4;
            {   int iL = r >> 5, jL = r & 31;
                float4 v = *(const float4*)(W1
                    + ((long)(i0g + iL) * 128 + (j0g + jL)) * 512 + c0 + c4);
                Asm[iL][jL][c4 + 0] = v.x; Asm[iL][jL][c4 + 1] = v.y;
                Asm[iL][jL][c4 + 2] = v.z; Asm[iL][jL][c4 + 3] = v.w;
            }
            {   int jL = r >> 2, iL = r & 3;
                float4 v = *(const float4*)(W1
                    + ((long)(j0g + jL) * 128 + (i0g + iL)) * 512 + c0 + c4);
                Bsm[jL][iL][c4 + 0] = v.x; Bsm[jL][iL][c4 + 1] = v.y;
                Bsm[jL][iL][c4 + 2] = v.z; Bsm[jL][iL][c4 + 3] = v.w;
            }
        }
        __syncthreads();
        const int w = tid >> 6, lane = tid & 63;
        const int m = lane & 15, quad = lane >> 4;
        const int c16 = cb * 4 + w;
        const int cl = w * 16 + m;
#pragma unroll
        for (int iL = 0; iL < 4; ++iL) {
            const int ig = i0g + iL;
            union { unsigned short s[8]; uint4 uu; } o;
#pragma unroll
            for (int e = 0; e < 8; ++e) {
                int jL = quad * 8 + e;
                int jg = j0g + jL;
                float v;
                if (jg > ig)      v = Asm[iL][jL][cl] + Bsm[jL][iL][cl];
                else if (jg == ig) v = Asm[iL][jL][cl];
                else               v = 0.f;
                o.s[e] = f2bf(v);
            }
            const int il = isub * 4 + iL;
            const long col = base + (long)il * stride;
            *(uint4*)(W1p + ((long)c16 * 320 + col) * 512 + lane * 8) = o.uu;
        }
    } else {
        const int t = bx - 640;                // 0..31
        const int r0 = (t & 7) * 64, c0 = (t >> 3) * 64;
        const int R = 512, C = 256;
        const int tr = tid >> 4;
        const int tc4 = (tid & 15) * 4;
#pragma unroll
        for (int pp = 0; pp < 4; ++pp) {
            int r = pp * 16 + tr;
            float4 v = *(const float4*)(W2 + (long)(r0 + r) * C + c0 + tc4);
            tile[r][tc4 + 0] = v.x; tile[r][tc4 + 1] = v.y;
            tile[r][tc4 + 2] = v.z; tile[r][tc4 + 3] = v.w;
        }
        __syncthreads();
#pragma unroll
        for (int pp = 0; pp < 4; ++pp) {
            int cc = pp * 16 + tr;
            union { unsigned short s[4]; uint2 u; } pk;
#pragma unroll
            for (int e = 0; e < 4; ++e) pk.s[e] = f2bf(tile[tc4 + e][cc]);
            *(uint2*)(W2T + (long)(c0 + cc) * R + r0 + tc4) = pk.u;
        }
    }
}

// ---------------------------------------------------------------------------
// gemm_sym: 256 thr = 4 waves (2wm c x 2wn b); wave c32 x b128 (tm=2,tn=8);
// block c64 x b256. Grid 512 flat; L=(n&7)*64+(n>>3): bx=L&15, s=L>>4,
// g=s&3 (unit group), cb=s>>2 (== XCD, A-slice 1.31MB L2-resident).
// Pb record (g,ct,bt) = 512B fragment-packed (v9-proven coalesced).

// PHASE2 step: CH=2 chained, per-il advance 1024 u16, wrap &31
#define A_STEP2(Ac00, Ac01, Ac10, Ac11, I)                                 \
    {                                                                      \
        float xi[8];                                                       \
        _Pragma("unroll")                                                  \
        for (int tn = 0; tn < 8; ++tn)                                     \
            xi[tn] = xT[bLloc + tn * 16][(I)];                             \
        _Pragma("unroll")                                                  \
        for (int tn = 0; tn < 8; ++tn) {                                   \
            floatx4 t0 = __builtin_amdgcn_mfma_f32_16x16x32_bf16(          \
                Ac00, Xf[0][tn], zero4, 0, 0, 0);                          \
            t0 = __builtin_amdgcn_mfma_f32_16x16x32_bf16(                  \
                Ac01, Xf[1][tn], t0, 0, 0, 0);                             \
            acc[0][tn] += xi[tn] * t0;                                     \
            floatx4 t1 = __builtin_amdgcn_mfma_f32_16x16x32_bf16(          \
                Ac10, Xf[0][tn], zero4, 0, 0, 0);                          \
            t1 = __builtin_amdgcn_mfma_f32_16x16x32_bf16(                  \
                Ac11, Xf[1][tn], t1, 0, 0, 0);                             \
            acc[1][tn] += xi[tn] * t1;                                     \
        }                                                                  \
        const int p_ = ((I) + 4) & 31; /* wrap: tail reload is harmless */ \
        Ac00 = *(const short8*)(aB00 + (long)p_ * 1024);                   \
        Ac01 = *(const short8*)(aB01 + (long)p_ * 1024);                   \
        Ac10 = *(const short8*)(aB10 + (long)p_ * 1024);                   \
        Ac11 = *(const short8*)(aB11 + (long)p_ * 1024);                   \
    }

// PHASE1H step: CH=1, per-il advance 512 u16, wrap &15 (always in-window)
#define H_STEP(Ac0, Ac1, I)                                                \
    {                                                                      \
        float xi[8];                                                       \
        _Pragma("unroll")                                                  \
        for (int tn = 0; tn < 8; ++tn)                                     \
            xi[tn] = xT[bLloc + tn * 16][(I)];                             \
        _Pragma("unroll")                                                  \
        for (int tn = 0; tn < 8; ++tn) {                                   \
            floatx4 t0 = __builtin_amdgcn_mfma_f32_16x16x32_bf16(          \
                Ac0, Xf[0][tn], zero4, 0, 0, 0);                           \
            acc[0][tn] += xi[tn] * t0;                                     \
            floatx4 t1 = __builtin_amdgcn_mfma_f32_16x16x32_bf16(          \
                Ac1, Xf[0][tn], zero4, 0, 0, 0);                           \
            acc[1][tn] += xi[tn] * t1;                                     \
        }                                                                  \
        const int p_ = ((I) + 4) & 15;                                     \
        Ac0 = *(const short8*)(aC0 + (long)p_ * 512);                      \
        Ac1 = *(const short8*)(aC1 + (long)p_ * 512);                      \
    }

__global__ __launch_bounds__(256, 2) void gemm_sym_kernel(
    const float* __restrict__ x,               // [4096][128]
    const unsigned short* __restrict__ W1p,
    unsigned short* __restrict__ Pb) {         // fragment-packed partials
    __shared__ float xT[256][34];
    const int tid = threadIdx.x;
    const int n = blockIdx.x;
    const int L = (n & 7) * 64 + (n >> 3);     // bijective, 512 blocks
    const int bx = L & 15;
    const int s = L >> 4;                      // 0..31
    const int g = s & 3;
    const int cb = s >> 2;                     // == XCD
    const int b0 = bx * 256;
    const int c0 = cb * 64;
    const int i0_2 = (g < 2) ? 0 : (g - 1) * 32;
    const int i0_1 = 32 + (g & 1) * 16 + (g >> 1) * 64;
    const int col2 = g * 64;
    const int col1 = 256 + g * 16;
    const int jc0 = (g == 0) ? 0 : (g == 2) ? 1 : 2;
    const int jc1 = (g == 0) ? 1 : (g == 2) ? 2 : 3;

    // stage 32-i slice for PHASE2
    for (int idx = tid; idx < 256 * 32; idx += 256) {
        int bL = idx >> 5, iL = idx & 31;
        xT[bL][iL] = x[(long)(b0 + bL) * 128 + i0_2 + iL];
    }
    __syncthreads();

    const int wid = tid >> 6;
    const int wm = wid >> 1, wn = wid & 1;
    const int lane = tid & 63;
    const int n16 = lane & 15, quad = lane >> 4;
    const int bBase = b0 + wn * 128;
    const int c16base = (c0 >> 4) + wm * 2;
    const int bLloc = wn * 128 + n16;

    floatx4 acc[2][8];
#pragma unroll
    for (int tm = 0; tm < 2; ++tm)
#pragma unroll
        for (int tn = 0; tn < 8; ++tn) acc[tm][tn] = (floatx4){0.f, 0.f, 0.f, 0.f};
    const floatx4 zero4 = (floatx4){0.f, 0.f, 0.f, 0.f};

    // x B-fragments for the two PHASE2 j-chunks
    short8 Xf[2][8];
#pragma unroll
    for (int ks = 0; ks < 2; ++ks) {
        const int jc = ks ? jc1 : jc0;
#pragma unroll
        for (int tn = 0; tn < 8; ++tn) {
            const float* xp = x + (long)(bBase + tn * 16 + n16) * 128
                                + jc * 32 + quad * 8;
            float4 v0 = *(const float4*)xp;
            float4 v1 = *(const float4*)(xp + 4);
            short8 f;
            f[0] = (short)f2bf(v0.x); f[1] = (short)f2bf(v0.y);
            f[2] = (short)f2bf(v0.z); f[3] = (short)f2bf(v0.w);
            f[4] = (short)f2bf(v1.x); f[5] = (short)f2bf(v1.y);
            f[6] = (short)f2bf(v1.z); f[7] = (short)f2bf(v1.w);
            Xf[ks][tn] = f;
        }
    }

    // ---- PHASE2: 32 il, CH=2 ----
    {
        const unsigned short* aB00 = W1p
            + ((long)(c16base + 0) * 320 + col2) * 512 + lane * 8;
        const unsigned short* aB01 = aB00 + 512;
        const unsigned short* aB10 = W1p
            + ((long)(c16base + 1) * 320 + col2) * 512 + lane * 8;
        const unsigned short* aB11 = aB10 + 512;

        short8 A0_00 = *(const short8*)(aB00);
        short8 A0_01 = *(const short8*)(aB01);
        short8 A0_10 = *(const short8*)(aB10);
        short8 A0_11 = *(const short8*)(aB11);
        short8 A1_00 = *(const short8*)(aB00 + 1 * 1024);
        short8 A1_01 = *(const short8*)(aB01 + 1 * 1024);
        short8 A1_10 = *(const short8*)(aB10 + 1 * 1024);
        short8 A1_11 = *(const short8*)(aB11 + 1 * 1024);
        short8 A2_00 = *(const short8*)(aB00 + 2 * 1024);
        short8 A2_01 = *(const short8*)(aB01 + 2 * 1024);
        short8 A2_10 = *(const short8*)(aB10 + 2 * 1024);
        short8 A2_11 = *(const short8*)(aB11 + 2 * 1024);
        short8 A3_00 = *(const short8*)(aB00 + 3 * 1024);
        short8 A3_01 = *(const short8*)(aB01 + 3 * 1024);
        short8 A3_10 = *(const short8*)(aB10 + 3 * 1024);
        short8 A3_11 = *(const short8*)(aB11 + 3 * 1024);

#pragma unroll 1
        for (int ib = 0; ib < 8; ++ib) {
            const int i = ib * 4;
            A_STEP2(A0_00, A0_01, A0_10, A0_11, i + 0)
            A_STEP2(A1_00, A1_01, A1_10, A1_11, i + 1)
            A_STEP2(A2_00, A2_01, A2_10, A2_11, i + 2)
            A_STEP2(A3_00, A3_01, A3_10, A3_11, i + 3)
        }
    }

    // restage 16-i slice for PHASE1H
    __syncthreads();
    for (int idx = tid; idx < 256 * 16; idx += 256) {
        int bL = idx >> 4, iL = idx & 15;
        xT[bL][iL] = x[(long)(b0 + bL) * 128 + i0_1 + iL];
    }
    __syncthreads();
    // reload Xf[0] from j-chunk 3 (PHASE1H operand)
#pragma unroll
    for (int tn = 0; tn < 8; ++tn) {
        const float* xp = x + (long)(bBase + tn * 16 + n16) * 128
                            + 3 * 32 + quad * 8;
        float4 v0 = *(const float4*)xp;
        float4 v1 = *(const float4*)(xp + 4);
        short8 f;
        f[0] = (short)f2bf(v0.x); f[1] = (short)f2bf(v0.y);
        f[2] = (short)f2bf(v0.z); f[3] = (short)f2bf(v0.w);
        f[4] = (short)f2bf(v1.x); f[5] = (short)f2bf(v1.y);
        f[6] = (short)f2bf(v1.z); f[7] = (short)f2bf(v1.w);
        Xf[0][tn] = f;
    }

    // ---- PHASE1H: 16 il, CH=1 ----
    {
        const unsigned short* aC0 = W1p
            + ((long)(c16base + 0) * 320 + col1) * 512 + lane * 8;
        const unsigned short* aC1 = W1p
            + ((long)(c16base + 1) * 320 + col1) * 512 + lane * 8;
        short8 C0_0 = *(const short8*)(aC0);
        short8 C0_1 = *(const short8*)(aC1);
        short8 C1_0 = *(const short8*)(aC0 + 1 * 512);
        short8 C1_1 = *(const short8*)(aC1 + 1 * 512);
        short8 C2_0 = *(const short8*)(aC0 + 2 * 512);
        short8 C2_1 = *(const short8*)(aC1 + 2 * 512);
        short8 C3_0 = *(const short8*)(aC0 + 3 * 512);
        short8 C3_1 = *(const short8*)(aC1 + 3 * 512);

#pragma unroll 1
        for (int ib = 0; ib < 4; ++ib) {
            const int i = ib * 4;
            H_STEP(C0_0, C0_1, i + 0)
            H_STEP(C1_0, C1_1, i + 1)
            H_STEP(C2_0, C2_1, i + 2)
            H_STEP(C3_0, C3_1, i + 3)
        }
    }

    // store bf16 partials, fragment-packed: record (g,ct,bt) = 512B
#pragma unroll
    for (int tm = 0; tm < 2; ++tm)
#pragma unroll
        for (int tn = 0; tn < 8; ++tn) {
            int ct = c16base + tm;                 // 0..31
            int bt = (bBase >> 4) + tn;            // 0..255
            union { unsigned short s[4]; uint2 u; } pk;
#pragma unroll
            for (int r = 0; r < 4; ++r) pk.s[r] = f2bf(acc[tm][tn][r]);
            *(uint2*)(Pb + (((long)(g * 32 + ct) * 256 + bt) * 64 + lane) * 4)
                = pk.u;
        }
}

// ---------------------------------------------------------------------------
// tail (v9 byte-identical): z-reduce fragment-packed Pb in-register,
// h = relu(128*sum + b1) -> hL (bf16, LDS), then out = h @ W2T + b2.
__global__ __launch_bounds__(256) void tail_kernel(
    const unsigned short* __restrict__ Pb,     // fragment-packed partials
    const float* __restrict__ b1,              // [512]
    const unsigned short* __restrict__ W2T,    // [256][512] bf16
    const float* __restrict__ b2,              // [256]
    float* __restrict__ out) {                 // [4096][256]
    __shared__ unsigned short hL[16][516];
    __shared__ float b1s[512];
    const int tid = threadIdx.x;
    const int bt = blockIdx.x;                 // b0 = bt*16
    b1s[tid] = b1[tid];
    b1s[tid + 256] = b1[tid + 256];
    __syncthreads();

    const int w = tid >> 6, lane = tid & 63;
    const int n16 = lane & 15, quad = lane >> 4;

#pragma unroll
    for (int cc = 0; cc < 8; ++cc) {
        const int ct = cc * 4 + w;             // 0..31, wave-partitioned
        float s0 = 0.f, s1 = 0.f, s2 = 0.f, s3 = 0.f;
#pragma unroll
        for (int z = 0; z < 4; ++z) {
            uint2 u = *(const uint2*)(Pb
                + (((long)(z * 32 + ct) * 256 + bt) * 64 + lane) * 4);
            s0 += bf2f((unsigned short)(u.x & 0xffff));
            s1 += bf2f((unsigned short)(u.x >> 16));
            s2 += bf2f((unsigned short)(u.y & 0xffff));
            s3 += bf2f((unsigned short)(u.y >> 16));
        }
        const int c = ct * 16 + quad * 4;
        float v0 = fmaxf(fmaf(128.f, s0, b1s[c + 0]), 0.f);
        float v1 = fmaxf(fmaf(128.f, s1, b1s[c + 1]), 0.f);
        float v2 = fmaxf(fmaf(128.f, s2, b1s[c + 2]), 0.f);
        float v3 = fmaxf(fmaf(128.f, s3, b1s[c + 3]), 0.f);
        union { unsigned short s[4]; uint2 u; } pk;
        pk.s[0] = f2bf(v0); pk.s[1] = f2bf(v1);
        pk.s[2] = f2bf(v2); pk.s[3] = f2bf(v3);
        *(uint2*)&hL[n16][c] = pk.u;
    }
    __syncthreads();

    const int o0 = w * 64;
    floatx4 acc[4];
#pragma unroll
    for (int tn = 0; tn < 4; ++tn) acc[tn] = (floatx4){0.f, 0.f, 0.f, 0.f};

#pragma unroll 4
    for (int ks = 0; ks < 16; ++ks) {
        short8 Af, Bf[4];
        {
            const unsigned short* p = &hL[n16][ks * 32 + quad * 8];
            union { uint2 u[2]; short8 s; } cvt;
            cvt.u[0] = *(const uint2*)p;
            cvt.u[1] = *(const uint2*)(p + 4);
            Af = cvt.s;
        }
#pragma unroll
        for (int tn = 0; tn < 4; ++tn)
            Bf[tn] = *(const short8*)(W2T + (long)(o0 + tn * 16 + n16) * 512
                                      + ks * 32 + quad * 8);
#pragma unroll
        for (int tn = 0; tn < 4; ++tn)
            acc[tn] = __builtin_amdgcn_mfma_f32_16x16x32_bf16(
                Af, Bf[tn], acc[tn], 0, 0, 0);
    }
#pragma unroll
    for (int tn = 0; tn < 4; ++tn) {
        float bias = b2[o0 + tn * 16 + n16];
#pragma unroll
        for (int r = 0; r < 4; ++r)
            out[(long)(bt * 16 + quad * 4 + r) * 256
                + o0 + tn * 16 + n16] = acc[tn][r] + bias;
    }
}

extern "C" void kernel_launch(void* const* d_in, const int* in_sizes, int n_in,
                              void* d_out, int out_size, void* d_ws, size_t ws_size,
                              hipStream_t stream) {
    const float* x  = (const float*)d_in[0];   // [4096,128]
    const float* W1 = (const float*)d_in[1];   // [16384,512]
    const float* b1 = (const float*)d_in[2];   // [512]
    const float* W2 = (const float*)d_in[3];   // [512,256]
    const float* b2 = (const float*)d_in[4];   // [256]
    float* out = (float*)d_out;                // [4096,256]

    char* ws = (char*)d_ws;
    unsigned short* W1p = (unsigned short*)(ws);                  // 10.49 MB
    unsigned short* W2T = (unsigned short*)(ws + 10485760);       // 0.26 MB
    unsigned short* Pb  = (unsigned short*)(ws + 10485760 + 262144); // 16.78 MB

    prep_kernel<<<dim3(672), 256, 0, stream>>>(W1, W1p, W2, W2T);
    gemm_sym_kernel<<<dim3(512), 256, 0, stream>>>(x, W1p, Pb);
    tail_kernel<<<dim3(256), 256, 0, stream>>>(Pb, b1, W2T, b2, out);
}

// Round 11
// 150.450 us; speedup vs baseline: 1.2378x; 1.0303x over previous
//
#include <hip/hip_runtime.h>
#include <hip/hip_bf16.h>

// SO3TensorProductLayer: out = relu(128*(x (x) x) @ W1 + b1) @ W2 + b2
// v13 (resubmit — round 10 was an infra failure, container never ran):
// v11 (155us, passed) with a zero-LDS direct-read prep.
// v12 post-mortem: cooperative fusion produced zeros (launch rejected /
// never ran) -> one strike, reverted. v11 budget: gemm 57us + non-gemm
// 98us; prep (640 blocks, 64KB LDS staging, sync-heavy, 2 blocks/CU)
// is the largest unmeasured item. Both fold operands W1[(i*128+j)*512+c]
// and W1[(j*128+i)*512+c] are c-contiguous -> wave reads (m->c, quad->j)
// coalesce to 4x64B segments per instruction DIRECTLY from global: no
// LDS, no syncthreads, uniform conditions off-diag, exec-mask on the 4
// diag units. W1p layout byte-identical to v11 -> gemm/tail untouched.
// gemm_sym + tail = v11 verbatim (absmax 1.0 proven).
// REGALLOC (r5/rule20): no runtime-indexed vector arrays; named rings.

typedef __attribute__((ext_vector_type(8))) short short8;   // 8 bf16
typedef __attribute__((ext_vector_type(4))) float floatx4;  // 4 fp32

__device__ __forceinline__ unsigned short f2bf(float f) {
    union { float f; unsigned int u; } v; v.f = f;
    unsigned int r = v.u + 0x7fffu + ((v.u >> 16) & 1u);   // RNE
    return (unsigned short)(r >> 16);
}
__device__ __forceinline__ float bf2f(unsigned short b) {
    union { unsigned int u; float f; } v; v.u = ((unsigned int)b) << 16;
    return v.f;
}

// ---------------------------------------------------------------------------
// prep v13: blocks 0..639 pack symmetric-folded W1 -> W1p (direct global
// reads, no LDS); 640..671 transpose W2 -> W2T bf16.
// Task (u, isub, cb): u = (z,kc) unit, isub = 4-i subchunk, cb = 64-c blk.
// Wave w -> c16 = cb*4+w; per iL: chunk(c16, i=z*32+isub*4+iL, kc), lane
// (m=lane&15, quad) elem e = W1s[j=kc*32+quad*8+e][i][c16*16+m], where
// W1s = W1[ij]+W1[ji] (j>i), W1[ii] (j==i), 0 (j<i).
// col = base + il*stride (v11 layout): z=0: (kc>>1)*64+(kc&1),2;
// z=1,kc<3: 128+(kc-1),2; z=1,kc=3: 256,1; z=2: 192+(kc-2),2; z=3: 288,1.
__global__ __launch_bounds__(256) void prep_kernel(
    const float* __restrict__ W1, unsigned short* __restrict__ W1p,
    const float* __restrict__ W2, unsigned short* __restrict__ W2T) {
    __shared__ float tile[64][65];
    const int bx = blockIdx.x;
    const int tid = threadIdx.x;
    if (bx < 640) {
        const int u = bx >> 6;
        const int rem = bx & 63;
        const int isub = rem >> 3, cb = rem & 7;
        const int z  = (u < 4) ? 0 : (u < 7) ? 1 : (u < 9) ? 2 : 3;
        const int kc = (u < 4) ? u : (u < 7) ? (u - 3) : (u < 9) ? (u - 5) : 3;
        int base, stride;
        if (z == 0)                { base = (kc >> 1) * 64 + (kc & 1); stride = 2; }
        else if (z == 1 && kc < 3) { base = 128 + (kc - 1);            stride = 2; }
        else if (z == 1)           { base = 256;                       stride = 1; }
        else if (z == 2)           { base = 192 + (kc - 2);            stride = 2; }
        else                       { base = 288;                       stride = 1; }
        const int j0g = kc * 32;
        const int w = tid >> 6, lane = tid & 63;
        const int m = lane & 15, quad = lane >> 4;
        const int c16 = cb * 4 + w;
        const int c = c16 * 16 + m;                // global c for this lane
#pragma unroll
        for (int iL = 0; iL < 4; ++iL) {
            const int il = isub * 4 + iL;
            const int ig = z * 32 + il;
            union { unsigned short s[8]; uint4 uu; } o;
#pragma unroll
            for (int e = 0; e < 8; ++e) {
                const int jg = j0g + quad * 8 + e;
                float a = 0.f, b = 0.f;
                if (jg >= ig)                       // uniform when z<kc
                    a = W1[((long)ig * 128 + jg) * 512 + c];
                if (jg > ig)
                    b = W1[((long)jg * 128 + ig) * 512 + c];
                o.s[e] = f2bf(a + b);
            }
            const long col = base + (long)il * stride;
            *(uint4*)(W1p + ((long)c16 * 320 + col) * 512 + lane * 8) = o.uu;
        }
    } else {
        const int t = bx - 640;                // 0..31
        const int r0 = (t & 7) * 64, c0 = (t >> 3) * 64;
        const int R = 512, C = 256;
        const int tr = tid >> 4;
        const int tc4 = (tid & 15) * 4;
#pragma unroll
        for (int pp = 0; pp < 4; ++pp) {
            int r = pp * 16 + tr;
            float4 v = *(const float4*)(W2 + (long)(r0 + r) * C + c0 + tc4);
            tile[r][tc4 + 0] = v.x; tile[r][tc4 + 1] = v.y;
            tile[r][tc4 + 2] = v.z; tile[r][tc4 + 3] = v.w;
        }
        __syncthreads();
#pragma unroll
        for (int pp = 0; pp < 4; ++pp) {
            int cc = pp * 16 + tr;
            union { unsigned short s[4]; uint2 u; } pk;
#pragma unroll
            for (int e = 0; e < 4; ++e) pk.s[e] = f2bf(tile[tc4 + e][cc]);
            *(uint2*)(W2T + (long)(c0 + cc) * R + r0 + tc4) = pk.u;
        }
    }
}

// ---------------------------------------------------------------------------
// gemm_sym (v11 verbatim): 256 thr = 4 waves (2wm c x 2wn b); wave c32 x
// b128 (tm=2,tn=8); block c64 x b256. Grid 512 flat; L=(n&7)*64+(n>>3):
// bx=L&15, s=L>>4, g=s&3 (unit group), cb=s>>2 (== XCD, A-slice 1.31MB
// L2-resident). Pb record (g,ct,bt) = 512B fragment-packed.

// PHASE2 step: CH=2 chained, per-il advance 1024 u16, wrap &31
#define A_STEP2(Ac00, Ac01, Ac10, Ac11, I)                                 \
    {                                                                      \
        float xi[8];                                                       \
        _Pragma("unroll")                                                  \
        for (int tn = 0; tn < 8; ++tn)                                     \
            xi[tn] = xT[bLloc + tn * 16][(I)];                             \
        _Pragma("unroll")                                                  \
        for (int tn = 0; tn < 8; ++tn) {                                   \
            floatx4 t0 = __builtin_amdgcn_mfma_f32_16x16x32_bf16(          \
                Ac00, Xf[0][tn], zero4, 0, 0, 0);                          \
            t0 = __builtin_amdgcn_mfma_f32_16x16x32_bf16(                  \
                Ac01, Xf[1][tn], t0, 0, 0, 0);                             \
            acc[0][tn] += xi[tn] * t0;                                     \
            floatx4 t1 = __builtin_amdgcn_mfma_f32_16x16x32_bf16(          \
                Ac10, Xf[0][tn], zero4, 0, 0, 0);                          \
            t1 = __builtin_amdgcn_mfma_f32_16x16x32_bf16(                  \
                Ac11, Xf[1][tn], t1, 0, 0, 0);                             \
            acc[1][tn] += xi[tn] * t1;                                     \
        }                                                                  \
        const int p_ = ((I) + 4) & 31; /* wrap: tail reload is harmless */ \
        Ac00 = *(const short8*)(aB00 + (long)p_ * 1024);                   \
        Ac01 = *(const short8*)(aB01 + (long)p_ * 1024);                   \
        Ac10 = *(const short8*)(aB10 + (long)p_ * 1024);                   \
        Ac11 = *(const short8*)(aB11 + (long)p_ * 1024);                   \
    }

// PHASE1H step: CH=1, per-il advance 512 u16, wrap &15
#define H_STEP(Ac0, Ac1, I)                                                \
    {                                                                      \
        float xi[8];                                                       \
        _Pragma("unroll")                                                  \
        for (int tn = 0; tn < 8; ++tn)                                     \
            xi[tn] = xT[bLloc + tn * 16][(I)];                             \
        _Pragma("unroll")                                                  \
        for (int tn = 0; tn < 8; ++tn) {                                   \
            floatx4 t0 = __builtin_amdgcn_mfma_f32_16x16x32_bf16(          \
                Ac0, Xf[0][tn], zero4, 0, 0, 0);                           \
            acc[0][tn] += xi[tn] * t0;                                     \
            floatx4 t1 = __builtin_amdgcn_mfma_f32_16x16x32_bf16(          \
                Ac1, Xf[0][tn], zero4, 0, 0, 0);                           \
            acc[1][tn] += xi[tn] * t1;                                     \
        }                                                                  \
        const int p_ = ((I) + 4) & 15;                                     \
        Ac0 = *(const short8*)(aC0 + (long)p_ * 512);                      \
        Ac1 = *(const short8*)(aC1 + (long)p_ * 512);                      \
    }

__global__ __launch_bounds__(256, 2) void gemm_sym_kernel(
    const float* __restrict__ x,               // [4096][128]
    const unsigned short* __restrict__ W1p,
    unsigned short* __restrict__ Pb) {         // fragment-packed partials
    __shared__ float xT[256][34];
    const int tid = threadIdx.x;
    const int n = blockIdx.x;
    const int L = (n & 7) * 64 + (n >> 3);     // bijective, 512 blocks
    const int bx = L & 15;
    const int s = L >> 4;                      // 0..31
    const int g = s & 3;
    const int cb = s >> 2;                     // == XCD
    const int b0 = bx * 256;
    const int c0 = cb * 64;
    const int i0_2 = (g < 2) ? 0 : (g - 1) * 32;
    const int i0_1 = 32 + (g & 1) * 16 + (g >> 1) * 64;
    const int col2 = g * 64;
    const int col1 = 256 + g * 16;
    const int jc0 = (g == 0) ? 0 : (g == 2) ? 1 : 2;
    const int jc1 = (g == 0) ? 1 : (g == 2) ? 2 : 3;

    // stage 32-i slice for PHASE2
    for (int idx = tid; idx < 256 * 32; idx += 256) {
        int bL = idx >> 5, iL = idx & 31;
        xT[bL][iL] = x[(long)(b0 + bL) * 128 + i0_2 + iL];
    }
    __syncthreads();

    const int wid = tid >> 6;
    const int wm = wid >> 1, wn = wid & 1;
    const int lane = tid & 63;
    const int n16 = lane & 15, quad = lane >> 4;
    const int bBase = b0 + wn * 128;
    const int c16base = (c0 >> 4) + wm * 2;
    const int bLloc = wn * 128 + n16;

    floatx4 acc[2][8];
#pragma unroll
    for (int tm = 0; tm < 2; ++tm)
#pragma unroll
        for (int tn = 0; tn < 8; ++tn) acc[tm][tn] = (floatx4){0.f, 0.f, 0.f, 0.f};
    const floatx4 zero4 = (floatx4){0.f, 0.f, 0.f, 0.f};

    // x B-fragments for the two PHASE2 j-chunks
    short8 Xf[2][8];
#pragma unroll
    for (int ks = 0; ks < 2; ++ks) {
        const int jc = ks ? jc1 : jc0;
#pragma unroll
        for (int tn = 0; tn < 8; ++tn) {
            const float* xp = x + (long)(bBase + tn * 16 + n16) * 128
                                + jc * 32 + quad * 8;
            float4 v0 = *(const float4*)xp;
            float4 v1 = *(const float4*)(xp + 4);
            short8 f;
            f[0] = (short)f2bf(v0.x); f[1] = (short)f2bf(v0.y);
            f[2] = (short)f2bf(v0.z); f[3] = (short)f2bf(v0.w);
            f[4] = (short)f2bf(v1.x); f[5] = (short)f2bf(v1.y);
            f[6] = (short)f2bf(v1.z); f[7] = (short)f2bf(v1.w);
            Xf[ks][tn] = f;
        }
    }

    // ---- PHASE2: 32 il, CH=2 ----
    {
        const unsigned short* aB00 = W1p
            + ((long)(c16base + 0) * 320 + col2) * 512 + lane * 8;
        const unsigned short* aB01 = aB00 + 512;
        const unsigned short* aB10 = W1p
            + ((long)(c16base + 1) * 320 + col2) * 512 + lane * 8;
        const unsigned short* aB11 = aB10 + 512;

        short8 A0_00 = *(const short8*)(aB00);
        short8 A0_01 = *(const short8*)(aB01);
        short8 A0_10 = *(const short8*)(aB10);
        short8 A0_11 = *(const short8*)(aB11);
        short8 A1_00 = *(const short8*)(aB00 + 1 * 1024);
        short8 A1_01 = *(const short8*)(aB01 + 1 * 1024);
        short8 A1_10 = *(const short8*)(aB10 + 1 * 1024);
        short8 A1_11 = *(const short8*)(aB11 + 1 * 1024);
        short8 A2_00 = *(const short8*)(aB00 + 2 * 1024);
        short8 A2_01 = *(const short8*)(aB01 + 2 * 1024);
        short8 A2_10 = *(const short8*)(aB10 + 2 * 1024);
        short8 A2_11 = *(const short8*)(aB11 + 2 * 1024);
        short8 A3_00 = *(const short8*)(aB00 + 3 * 1024);
        short8 A3_01 = *(const short8*)(aB01 + 3 * 1024);
        short8 A3_10 = *(const short8*)(aB10 + 3 * 1024);
        short8 A3_11 = *(const short8*)(aB11 + 3 * 1024);

#pragma unroll 1
        for (int ib = 0; ib < 8; ++ib) {
            const int i = ib * 4;
            A_STEP2(A0_00, A0_01, A0_10, A0_11, i + 0)
            A_STEP2(A1_00, A1_01, A1_10, A1_11, i + 1)
            A_STEP2(A2_00, A2_01, A2_10, A2_11, i + 2)
            A_STEP2(A3_00, A3_01, A3_10, A3_11, i + 3)
        }
    }

    // restage 16-i slice for PHASE1H
    __syncthreads();
    for (int idx = tid; idx < 256 * 16; idx += 256) {
        int bL = idx >> 4, iL = idx & 15;
        xT[bL][iL] = x[(long)(b0 + bL) * 128 + i0_1 + iL];
    }
    __syncthreads();
    // reload Xf[0] from j-chunk 3 (PHASE1H operand)
#pragma unroll
    for (int tn = 0; tn < 8; ++tn) {
        const float* xp = x + (long)(bBase + tn * 16 + n16) * 128
                            + 3 * 32 + quad * 8;
        float4 v0 = *(const float4*)xp;
        float4 v1 = *(const float4*)(xp + 4);
        short8 f;
        f[0] = (short)f2bf(v0.x); f[1] = (short)f2bf(v0.y);
        f[2] = (short)f2bf(v0.z); f[3] = (short)f2bf(v0.w);
        f[4] = (short)f2bf(v1.x); f[5] = (short)f2bf(v1.y);
        f[6] = (short)f2bf(v1.z); f[7] = (short)f2bf(v1.w);
        Xf[0][tn] = f;
    }

    // ---- PHASE1H: 16 il, CH=1 ----
    {
        const unsigned short* aC0 = W1p
            + ((long)(c16base + 0) * 320 + col1) * 512 + lane * 8;
        const unsigned short* aC1 = W1p
            + ((long)(c16base + 1) * 320 + col1) * 512 + lane * 8;
        short8 C0_0 = *(const short8*)(aC0);
        short8 C0_1 = *(const short8*)(aC1);
        short8 C1_0 = *(const short8*)(aC0 + 1 * 512);
        short8 C1_1 = *(const short8*)(aC1 + 1 * 512);
        short8 C2_0 = *(const short8*)(aC0 + 2 * 512);
        short8 C2_1 = *(const short8*)(aC1 + 2 * 512);
        short8 C3_0 = *(const short8*)(aC0 + 3 * 512);
        short8 C3_1 = *(const short8*)(aC1 + 3 * 512);

#pragma unroll 1
        for (int ib = 0; ib < 4; ++ib) {
            const int i = ib * 4;
            H_STEP(C0_0, C0_1, i + 0)
            H_STEP(C1_0, C1_1, i + 1)
            H_STEP(C2_0, C2_1, i + 2)
            H_STEP(C3_0, C3_1, i + 3)
        }
    }

    // store bf16 partials, fragment-packed: record (g,ct,bt) = 512B
#pragma unroll
    for (int tm = 0; tm < 2; ++tm)
#pragma unroll
        for (int tn = 0; tn < 8; ++tn) {
            int ct = c16base + tm;                 // 0..31
            int bt = (bBase >> 4) + tn;            // 0..255
            union { unsigned short s[4]; uint2 u; } pk;
#pragma unroll
            for (int r = 0; r < 4; ++r) pk.s[r] = f2bf(acc[tm][tn][r]);
            *(uint2*)(Pb + (((long)(g * 32 + ct) * 256 + bt) * 64 + lane) * 4)
                = pk.u;
        }
}

// ---------------------------------------------------------------------------
// tail (v9/v11 verbatim): z-reduce fragment-packed Pb in-register,
// h = relu(128*sum + b1) -> hL (bf16, LDS), then out = h @ W2T + b2.
__global__ __launch_bounds__(256) void tail_kernel(
    const unsigned short* __restrict__ Pb,     // fragment-packed partials
    const float* __restrict__ b1,              // [512]
    const unsigned short* __restrict__ W2T,    // [256][512] bf16
    const float* __restrict__ b2,              // [256]
    float* __restrict__ out) {                 // [4096][256]
    __shared__ unsigned short hL[16][516];
    __shared__ float b1s[512];
    const int tid = threadIdx.x;
    const int bt = blockIdx.x;                 // b0 = bt*16
    b1s[tid] = b1[tid];
    b1s[tid + 256] = b1[tid + 256];
    __syncthreads();

    const int w = tid >> 6, lane = tid & 63;
    const int n16 = lane & 15, quad = lane >> 4;

#pragma unroll
    for (int cc = 0; cc < 8; ++cc) {
        const int ct = cc * 4 + w;             // 0..31, wave-partitioned
        float s0 = 0.f, s1 = 0.f, s2 = 0.f, s3 = 0.f;
#pragma unroll
        for (int z = 0; z < 4; ++z) {
            uint2 u = *(const uint2*)(Pb
                + (((long)(z * 32 + ct) * 256 + bt) * 64 + lane) * 4);
            s0 += bf2f((unsigned short)(u.x & 0xffff));
            s1 += bf2f((unsigned short)(u.x >> 16));
            s2 += bf2f((unsigned short)(u.y & 0xffff));
            s3 += bf2f((unsigned short)(u.y >> 16));
        }
        const int c = ct * 16 + quad * 4;
        float v0 = fmaxf(fmaf(128.f, s0, b1s[c + 0]), 0.f);
        float v1 = fmaxf(fmaf(128.f, s1, b1s[c + 1]), 0.f);
        float v2 = fmaxf(fmaf(128.f, s2, b1s[c + 2]), 0.f);
        float v3 = fmaxf(fmaf(128.f, s3, b1s[c + 3]), 0.f);
        union { unsigned short s[4]; uint2 u; } pk;
        pk.s[0] = f2bf(v0); pk.s[1] = f2bf(v1);
        pk.s[2] = f2bf(v2); pk.s[3] = f2bf(v3);
        *(uint2*)&hL[n16][c] = pk.u;
    }
    __syncthreads();

    const int o0 = w * 64;
    floatx4 acc[4];
#pragma unroll
    for (int tn = 0; tn < 4; ++tn) acc[tn] = (floatx4){0.f, 0.f, 0.f, 0.f};

#pragma unroll 4
    for (int ks = 0; ks < 16; ++ks) {
        short8 Af, Bf[4];
        {
            const unsigned short* p = &hL[n16][ks * 32 + quad * 8];
            union { uint2 u[2]; short8 s; } cvt;
            cvt.u[0] = *(const uint2*)p;
            cvt.u[1] = *(const uint2*)(p + 4);
            Af = cvt.s;
        }
#pragma unroll
        for (int tn = 0; tn < 4; ++tn)
            Bf[tn] = *(const short8*)(W2T + (long)(o0 + tn * 16 + n16) * 512
                                      + ks * 32 + quad * 8);
#pragma unroll
        for (int tn = 0; tn < 4; ++tn)
            acc[tn] = __builtin_amdgcn_mfma_f32_16x16x32_bf16(
                Af, Bf[tn], acc[tn], 0, 0, 0);
    }
#pragma unroll
    for (int tn = 0; tn < 4; ++tn) {
        float bias = b2[o0 + tn * 16 + n16];
#pragma unroll
        for (int r = 0; r < 4; ++r)
            out[(long)(bt * 16 + quad * 4 + r) * 256
                + o0 + tn * 16 + n16] = acc[tn][r] + bias;
    }
}

extern "C" void kernel_launch(void* const* d_in, const int* in_sizes, int n_in,
                              void* d_out, int out_size, void* d_ws, size_t ws_size,
                              hipStream_t stream) {
    const float* x  = (const float*)d_in[0];   // [4096,128]
    const float* W1 = (const float*)d_in[1];   // [16384,512]
    const float* b1 = (const float*)d_in[2];   // [512]
    const float* W2 = (const float*)d_in[3];   // [512,256]
    const float* b2 = (const float*)d_in[4];   // [256]
    float* out = (float*)d_out;                // [4096,256]

    char* ws = (char*)d_ws;
    unsigned short* W1p = (unsigned short*)(ws);                  // 10.49 MB
    unsigned short* W2T = (unsigned short*)(ws + 10485760);       // 0.26 MB
    unsigned short* Pb  = (unsigned short*)(ws + 10485760 + 262144); // 16.78 MB

    prep_kernel<<<dim3(672), 256, 0, stream>>>(W1, W1p, W2, W2T);
    gemm_sym_kernel<<<dim3(512), 256, 0, stream>>>(x, W1p, Pb);
    tail_kernel<<<dim3(256), 256, 0, stream>>>(Pb, b1, W2T, b2, out);
}